// Round 7
// baseline (50874.677 us; speedup 1.0000x reference)
//
#include <hip/hip_runtime.h>
#include <math.h>

#define BATCH 32
#define TLEN  512
#define HID   1024
#define G2    2048   // 2*H

// ---------------------------------------------------------------------------
// Projection GEMM: Cw[t][b][n] = sum_k A[m][k] * W[n][k],  m = b*TLEN + t
// Output permuted to [T][B][2H] so the recurrence reads contiguous slabs.
// ---------------------------------------------------------------------------
__global__ __launch_bounds__(256)
void proj_gemm(const float* __restrict__ A, const float* __restrict__ W,
               float* __restrict__ Cw, int K) {
    __shared__ float As[16][132];
    __shared__ float Bs[16][132];

    const int bm = blockIdx.x;
    const int bn = blockIdx.y;
    const int tid = threadIdx.x;
    const int tx = tid & 15;
    const int ty = tid >> 4;

    const int row0 = bm * 128;
    const int col0 = bn * 128;

    float acc[8][8];
    #pragma unroll
    for (int i = 0; i < 8; ++i)
        #pragma unroll
        for (int j = 0; j < 8; ++j) acc[i][j] = 0.f;

    for (int k0 = 0; k0 < K; k0 += 16) {
        #pragma unroll
        for (int i = 0; i < 2; ++i) {
            int f = tid + i * 256;
            int r = f >> 2;
            int c = (f & 3) * 4;
            float4 va = *(const float4*)&A[(size_t)(row0 + r) * K + k0 + c];
            As[c + 0][r] = va.x; As[c + 1][r] = va.y;
            As[c + 2][r] = va.z; As[c + 3][r] = va.w;
            float4 vb = *(const float4*)&W[(size_t)(col0 + r) * K + k0 + c];
            Bs[c + 0][r] = vb.x; Bs[c + 1][r] = vb.y;
            Bs[c + 2][r] = vb.z; Bs[c + 3][r] = vb.w;
        }
        __syncthreads();

        #pragma unroll
        for (int kk = 0; kk < 16; ++kk) {
            float a[8], b[8];
            #pragma unroll
            for (int i = 0; i < 8; ++i) a[i] = As[kk][ty * 8 + i];
            #pragma unroll
            for (int j = 0; j < 8; ++j) b[j] = Bs[kk][tx * 8 + j];
            #pragma unroll
            for (int i = 0; i < 8; ++i)
                #pragma unroll
                for (int j = 0; j < 8; ++j)
                    acc[i][j] += a[i] * b[j];
        }
        __syncthreads();
    }

    #pragma unroll
    for (int i = 0; i < 8; ++i) {
        int m = row0 + ty * 8 + i;
        int t = m & (TLEN - 1);
        int bb = m >> 9;
        float* dst = &Cw[((size_t)t * BATCH + bb) * G2 + col0 + tx * 8];
        #pragma unroll
        for (int j = 0; j < 8; ++j) dst[j] = acc[i][j];
    }
}

// ---------------------------------------------------------------------------
// Agent-scope (device-coherent) helpers: global_load/store sc0 sc1 (bypass
// L1/L2, hit LLC). No fences, no cache-maintenance ops.
// ---------------------------------------------------------------------------
__device__ __forceinline__ void st_flag(int* p, int v) {
    __hip_atomic_store(p, v, __ATOMIC_RELAXED, __HIP_MEMORY_SCOPE_AGENT);
}
__device__ __forceinline__ int ld_flag(const int* p) {
    return __hip_atomic_load(p, __ATOMIC_RELAXED, __HIP_MEMORY_SCOPE_AGENT);
}
__device__ __forceinline__ void st_h(float* p, float v) {
    __hip_atomic_store(p, v, __ATOMIC_RELAXED, __HIP_MEMORY_SCOPE_AGENT);
}
__device__ __forceinline__ uint64_t ld_h2(const float* p) {
    return __hip_atomic_load((const uint64_t*)p, __ATOMIC_RELAXED,
                             __HIP_MEMORY_SCOPE_AGENT);
}

#define NWG 256
#define FSTRIDE 16   // flags 64 B apart
#define BT 4         // batches per WG
#define JT 32        // j-outputs per WG
#define BHID (BATCH * HID)

__global__ void rec_init(float* h0, int* flags) {
    int i = blockIdx.x * 256 + threadIdx.x;
    if (i < BHID) h0[i] = 0.f;
    if (i < NWG * FSTRIDE) flags[i] = 0;
}

// ---------------------------------------------------------------------------
// Recurrence with GROUP-LOCAL sync (R6 structure) + register-blocked MAC.
// WG wg: bt = wg&7 (batch group), jb = wg>>3. WG owns batches [bt*4,bt*4+4)
// x gates [jb*32,+32). h in 3-deep ring; one flag store + one poll per step.
//
// MAC register blocking: thread = (wave wv 0..7, gate-group gg = lane&15,
// k-quarter kq = lane>>4). Thread owns 4 gate-rows x 4 batches x 32 k
// (k = wv*128 + i*16 + kq*4 + c). Per 4-k iter: 4 ds_read_b128 -> 64 FMA
// (1 B LDS per FMA, 4x fewer LDS instrs than R6). U slice stays register-
// resident (float4 ureg[4][8], static-indexed). Wave-internal 2-round
// __shfl_xor folds the 4 k-quarters, so red[][] stays [8][64][4].
// ---------------------------------------------------------------------------
__global__ __launch_bounds__(512, 1)
void ligru_rec(const float* __restrict__ w,    // [T][B][2H]
               const float* __restrict__ U,    // [2H][H]
               float* __restrict__ hbuf,       // [3][B][H] ring
               int* __restrict__ flags,        // NWG*FSTRIDE, pre-zeroed
               float* __restrict__ out,        // [B][T][H]
               float* __restrict__ hlast) {    // [B][H]
    __shared__ float hsh[BT * HID];            // 16 KB staged h
    __shared__ float red[8][64][4];            // 8 KB wave partials

    const int wg  = blockIdx.x;
    const int tid = threadIdx.x;
    const int bt  = wg & 7;           // group id
    const int jb  = wg >> 3;          // 0..31
    const int j0  = jb * JT;
    const int bg0 = bt * BT;

    const int wv = tid >> 6;          // wave 0..7
    const int l  = tid & 63;
    const int gg = l & 15;            // gate-group: rows gg*4..gg*4+3
    const int kq = l >> 4;            // k-quarter within wave
    const int kbase = wv * 128 + kq * 4;

    // ---- U slice -> registers (once; interleaved k layout to match MAC)
    float4 ureg[4][8];
    #pragma unroll
    for (int g = 0; g < 4; ++g) {
        int r = gg * 4 + g;
        int urow = (r < 32) ? (j0 + r) : (HID + j0 + (r - 32));
        const float* up = &U[(size_t)urow * HID + kbase];
        #pragma unroll
        for (int i = 0; i < 8; ++i)
            ureg[g][i] = *(const float4*)&up[i * 16];
    }

    float* h_t = hbuf;
    float* h_n = hbuf + BHID;
    float* h_p = hbuf + 2 * BHID;

    for (int t = 0; t < TLEN; ++t) {
        // ---- prefetch w (independent of h; latency hides under poll)
        float wa = 0.f, wz = 0.f;
        if (tid < BT * JT) {
            int bl = tid >> 5;
            int jl = tid & 31;
            const float* wt = &w[((size_t)t * BATCH + bg0 + bl) * G2];
            wa = wt[j0 + jl];
            wz = wt[HID + j0 + jl];
        }

        // ---- wait for group peers to have published h(t)
        if (t > 0) {
            if (tid < 32) {
                const int* fp = &flags[(bt + (tid << 3)) * FSTRIDE];
                while (ld_flag(fp) < t)
                    __builtin_amdgcn_s_sleep(1);
            }
            __syncthreads();
        }

        // ---- stage h(t)[bg0..bg0+4][:] into LDS (16 KB, coherent)
        {
            const float* src = h_t + (size_t)bg0 * HID;
            #pragma unroll
            for (int c = 0; c < 2; ++c) {
                int off = c * 2048 + tid * 4;
                uint64_t u0 = ld_h2(src + off);
                uint64_t u1 = ld_h2(src + off + 2);
                float4 v;
                ((uint64_t*)&v)[0] = u0;
                ((uint64_t*)&v)[1] = u1;
                *(float4*)&hsh[off] = v;
            }
        }
        __syncthreads();

        // ---- MAC: 4 gate-rows x 4 batches x 32 k per thread
        float4 acc[4];
        #pragma unroll
        for (int g = 0; g < 4; ++g) acc[g] = make_float4(0.f, 0.f, 0.f, 0.f);
        {
            const float* hp = &hsh[kbase];
            #pragma unroll
            for (int i = 0; i < 8; ++i) {
                float4 h0v = *(const float4*)&hp[0 * HID + i * 16];
                float4 h1v = *(const float4*)&hp[1 * HID + i * 16];
                float4 h2v = *(const float4*)&hp[2 * HID + i * 16];
                float4 h3v = *(const float4*)&hp[3 * HID + i * 16];
                #pragma unroll
                for (int g = 0; g < 4; ++g) {
                    float4 uv = ureg[g][i];
                    acc[g].x += uv.x * h0v.x + uv.y * h0v.y + uv.z * h0v.z + uv.w * h0v.w;
                    acc[g].y += uv.x * h1v.x + uv.y * h1v.y + uv.z * h1v.z + uv.w * h1v.w;
                    acc[g].z += uv.x * h2v.x + uv.y * h2v.y + uv.z * h2v.z + uv.w * h2v.w;
                    acc[g].w += uv.x * h3v.x + uv.y * h3v.y + uv.z * h3v.z + uv.w * h3v.w;
                }
            }
        }

        // ---- fold k-quarters inside the wave (lane bits 4,5)
        #pragma unroll
        for (int g = 0; g < 4; ++g) {
            acc[g].x += __shfl_xor(acc[g].x, 16);
            acc[g].x += __shfl_xor(acc[g].x, 32);
            acc[g].y += __shfl_xor(acc[g].y, 16);
            acc[g].y += __shfl_xor(acc[g].y, 32);
            acc[g].z += __shfl_xor(acc[g].z, 16);
            acc[g].z += __shfl_xor(acc[g].z, 32);
            acc[g].w += __shfl_xor(acc[g].w, 16);
            acc[g].w += __shfl_xor(acc[g].w, 32);
        }
        if (l < 16) {
            #pragma unroll
            for (int g = 0; g < 4; ++g)
                *(float4*)&red[wv][gg * 4 + g][0] = acc[g];
        }
        __syncthreads();

        // ---- gates + state update (128 threads)
        if (tid < BT * JT) {
            int bl = tid >> 5;
            int jl = tid & 31;
            float sa = 0.f, sz = 0.f;
            #pragma unroll
            for (int k = 0; k < 8; ++k) {
                sa += red[k][jl][bl];
                sz += red[k][32 + jl][bl];
            }
            float at = wa + sa;
            float zt = wz + sz;
            zt = 1.f / (1.f + expf(-zt));
            float hc = tanhf(at);
            float hold = hsh[bl * HID + j0 + jl];
            float hnew = zt * hold + (1.f - zt) * hc;
            int bg = bg0 + bl;
            out[((size_t)bg * TLEN + t) * HID + j0 + jl] = hnew;     // plain
            if (t < TLEN - 1) {
                st_h(&h_n[(size_t)bg * HID + j0 + jl], hnew);        // coherent
            } else {
                hlast[(size_t)bg * HID + j0 + jl] = hnew;
            }
        }

        // ---- publish: one store; 3-deep ring makes WAR free
        if (t < TLEN - 1) {
            __syncthreads();   // drains vmcnt -> h stores at LLC
            if (tid == 0) st_flag(&flags[wg * FSTRIDE], t + 1);
        }

        float* tmp = h_t; h_t = h_n; h_n = h_p; h_p = tmp;
    }
}

// ---------------------------------------------------------------------------
extern "C" void kernel_launch(void* const* d_in, const int* in_sizes, int n_in,
                              void* d_out, int out_size, void* d_ws, size_t ws_size,
                              hipStream_t stream) {
    (void)in_sizes; (void)n_in; (void)out_size; (void)ws_size;

    const float* x  = (const float*)d_in[0];
    const float* W0 = (const float*)d_in[1];
    const float* U0 = (const float*)d_in[2];
    const float* W1 = (const float*)d_in[3];
    const float* U1 = (const float*)d_in[4];

    float* out    = (float*)d_out;                              // [B,T,H]
    float* hstack = out + (size_t)BATCH * TLEN * HID;           // [2,B,H]

    int*   flags = (int*)d_ws;                                  // 256*16 ints
    float* hbuf  = (float*)d_ws + NWG * FSTRIDE;                // [3][B][H]
    float* wbuf  = hbuf + 3 * BHID;                             // [T][B][2H]

    dim3 gg(16384 / 128, 2048 / 128);
    int init_blocks = (BHID + 255) / 256;

    // ---- layer 0 ----
    proj_gemm<<<gg, 256, 0, stream>>>(x, W0, wbuf, 512);
    rec_init<<<init_blocks, 256, 0, stream>>>(hbuf, flags);
    ligru_rec<<<dim3(NWG), dim3(512), 0, stream>>>(wbuf, U0, hbuf, flags,
                                                   out, hstack);

    // ---- layer 1 ---- (reads layer-0 output staged in d_out, then overwrites)
    proj_gemm<<<gg, 256, 0, stream>>>(out, W1, wbuf, 1024);
    rec_init<<<init_blocks, 256, 0, stream>>>(hbuf, flags);
    ligru_rec<<<dim3(NWG), dim3(512), 0, stream>>>(wbuf, U1, hbuf, flags,
                                                   out, hstack + BATCH * HID);
}

// Round 8
// 9002.962 us; speedup vs baseline: 5.6509x; 5.6509x over previous
//
#include <hip/hip_runtime.h>
#include <math.h>

#define BATCH 32
#define TLEN  512
#define HID   1024
#define G2    2048   // 2*H

// ---------------------------------------------------------------------------
// Projection GEMM: Cw[t][b][n] = sum_k A[m][k] * W[n][k],  m = b*TLEN + t
// Output permuted to [T][B][2H] so the recurrence reads contiguous slabs.
// ---------------------------------------------------------------------------
__global__ __launch_bounds__(256)
void proj_gemm(const float* __restrict__ A, const float* __restrict__ W,
               float* __restrict__ Cw, int K) {
    __shared__ float As[16][132];
    __shared__ float Bs[16][132];

    const int bm = blockIdx.x;
    const int bn = blockIdx.y;
    const int tid = threadIdx.x;
    const int tx = tid & 15;
    const int ty = tid >> 4;

    const int row0 = bm * 128;
    const int col0 = bn * 128;

    float acc[8][8];
    #pragma unroll
    for (int i = 0; i < 8; ++i)
        #pragma unroll
        for (int j = 0; j < 8; ++j) acc[i][j] = 0.f;

    for (int k0 = 0; k0 < K; k0 += 16) {
        #pragma unroll
        for (int i = 0; i < 2; ++i) {
            int f = tid + i * 256;
            int r = f >> 2;
            int c = (f & 3) * 4;
            float4 va = *(const float4*)&A[(size_t)(row0 + r) * K + k0 + c];
            As[c + 0][r] = va.x; As[c + 1][r] = va.y;
            As[c + 2][r] = va.z; As[c + 3][r] = va.w;
            float4 vb = *(const float4*)&W[(size_t)(col0 + r) * K + k0 + c];
            Bs[c + 0][r] = vb.x; Bs[c + 1][r] = vb.y;
            Bs[c + 2][r] = vb.z; Bs[c + 3][r] = vb.w;
        }
        __syncthreads();

        #pragma unroll
        for (int kk = 0; kk < 16; ++kk) {
            float a[8], b[8];
            #pragma unroll
            for (int i = 0; i < 8; ++i) a[i] = As[kk][ty * 8 + i];
            #pragma unroll
            for (int j = 0; j < 8; ++j) b[j] = Bs[kk][tx * 8 + j];
            #pragma unroll
            for (int i = 0; i < 8; ++i)
                #pragma unroll
                for (int j = 0; j < 8; ++j)
                    acc[i][j] += a[i] * b[j];
        }
        __syncthreads();
    }

    #pragma unroll
    for (int i = 0; i < 8; ++i) {
        int m = row0 + ty * 8 + i;
        int t = m & (TLEN - 1);
        int bb = m >> 9;
        float* dst = &Cw[((size_t)t * BATCH + bb) * G2 + col0 + tx * 8];
        #pragma unroll
        for (int j = 0; j < 8; ++j) dst[j] = acc[i][j];
    }
}

// ---------------------------------------------------------------------------
// Agent-scope (device-coherent) helpers: global_load/store sc0 sc1 (bypass
// L1/L2, hit LLC). No fences, no cache-maintenance ops.
// ---------------------------------------------------------------------------
__device__ __forceinline__ void st_flag(int* p, int v) {
    __hip_atomic_store(p, v, __ATOMIC_RELAXED, __HIP_MEMORY_SCOPE_AGENT);
}
__device__ __forceinline__ int ld_flag(const int* p) {
    return __hip_atomic_load(p, __ATOMIC_RELAXED, __HIP_MEMORY_SCOPE_AGENT);
}
__device__ __forceinline__ void st_h(float* p, float v) {
    __hip_atomic_store(p, v, __ATOMIC_RELAXED, __HIP_MEMORY_SCOPE_AGENT);
}
__device__ __forceinline__ uint64_t ld_h2(const float* p) {
    return __hip_atomic_load((const uint64_t*)p, __ATOMIC_RELAXED,
                             __HIP_MEMORY_SCOPE_AGENT);
}

#define NWG 256
#define FSTRIDE 16   // flags 64 B apart
#define NBT 4        // batch groups
#define BT 8         // batches per WG
#define JT 16        // j-outputs per WG
#define BHID (BATCH * HID)

__global__ void rec_init(float* h0, int* flags) {
    int i = blockIdx.x * 256 + threadIdx.x;
    if (i < BHID) h0[i] = 0.f;
    if (i < NWG * FSTRIDE) flags[i] = 0;
}

// ---------------------------------------------------------------------------
// Recurrence, group-local sync + register-blocked MAC, sized to AVOID SPILL.
// WG wg: bt = wg&3 (batch group, 4 groups x 64 WGs), jb = wg>>2 (0..63).
// WG owns batches [bt*8, bt*8+8) x gates [jb*16, jb*16+16) (32 U-rows:
// 16 a-rows + 16 z-rows).
//
// Thread: wv = tid>>6 (wave, k-128-range), lane = gg*8+kq (gg = gate-group
// of 4 rows, kq = k-octant within wave). Thread's k-elements:
// k = wv*128 + kq*4 + i*32, i=0..3 -> wave's 8 b128 addresses span all 32
// banks, conflict-free, 8-way broadcast. Per thread: 4 rows x 8 batches x
// 16 k = 512 FMA, 32 ds_read_b128 (1 B LDS per FMA). U slice = 16 float4
// (64 VGPR). acc = 32 floats. kq-octet folded by 3-round __shfl_xor.
// amdgpu_waves_per_eu(2,2): allocator budget 256 VGPR (we run 8 waves/CU
// = 2/EU anyway) -- prevents the R7 spill-at-128 failure.
// h in 3-deep ring; one flag store + one 64-flag poll per step (R6 scheme).
// ---------------------------------------------------------------------------
__global__ __launch_bounds__(512)
__attribute__((amdgpu_waves_per_eu(2, 2)))
void ligru_rec(const float* __restrict__ w,    // [T][B][2H]
               const float* __restrict__ U,    // [2H][H]
               float* __restrict__ hbuf,       // [3][B][H] ring
               int* __restrict__ flags,        // NWG*FSTRIDE, pre-zeroed
               float* __restrict__ out,        // [B][T][H]
               float* __restrict__ hlast) {    // [B][H]
    __shared__ float hsh[BT * HID];            // 32 KB staged h
    __shared__ float red[8][8][4][8];          // 8 KB wave partials

    const int wg  = blockIdx.x;
    const int tid = threadIdx.x;
    const int bt  = wg & 3;           // group id
    const int jb  = wg >> 2;          // 0..63
    const int j0  = jb * JT;
    const int bg0 = bt * BT;

    const int wv = tid >> 6;          // wave 0..7 (k-range wv*128..+128)
    const int l  = tid & 63;
    const int gg = l >> 3;            // gate-group: rows gg*4..gg*4+3
    const int kq = l & 7;             // k-octant within wave
    const int kbase = wv * 128 + kq * 4;

    // ---- U slice -> registers (16 float4 = 64 VGPR, static-indexed)
    float4 ureg[4][4];
    #pragma unroll
    for (int g = 0; g < 4; ++g) {
        int r = gg * 4 + g;           // 0..31
        int urow = (r < 16) ? (j0 + r) : (HID + j0 + (r - 16));
        const float* up = &U[(size_t)urow * HID + kbase];
        #pragma unroll
        for (int i = 0; i < 4; ++i)
            ureg[g][i] = *(const float4*)&up[i * 32];
    }

    float* h_t = hbuf;
    float* h_n = hbuf + BHID;
    float* h_p = hbuf + 2 * BHID;

    for (int t = 0; t < TLEN; ++t) {
        // ---- prefetch w (independent of h; latency hides under poll)
        float wa = 0.f, wz = 0.f;
        if (tid < BT * JT) {          // 128 gate threads
            int bl = tid >> 4;
            int jl = tid & 15;
            const float* wt = &w[((size_t)t * BATCH + bg0 + bl) * G2];
            wa = wt[j0 + jl];
            wz = wt[HID + j0 + jl];
        }

        // ---- wait for the 64 group peers to have published h(t)
        if (t > 0) {
            if (tid < 64) {
                const int* fp = &flags[(bt + (tid << 2)) * FSTRIDE];
                while (ld_flag(fp) < t)
                    __builtin_amdgcn_s_sleep(1);
            }
            __syncthreads();
        }

        // ---- stage h(t)[bg0..bg0+8][:] into LDS (32 KB, coherent)
        {
            const float* src = h_t + (size_t)bg0 * HID;
            #pragma unroll
            for (int c = 0; c < 4; ++c) {
                int off = c * 2048 + tid * 4;
                uint64_t u0 = ld_h2(src + off);
                uint64_t u1 = ld_h2(src + off + 2);
                float4 v;
                ((uint64_t*)&v)[0] = u0;
                ((uint64_t*)&v)[1] = u1;
                *(float4*)&hsh[off] = v;
            }
        }
        __syncthreads();

        // ---- MAC: 4 rows x 8 batches x 16 k per thread (1 B LDS / FMA)
        float accm[4][8];
        #pragma unroll
        for (int g = 0; g < 4; ++g)
            #pragma unroll
            for (int b = 0; b < 8; ++b) accm[g][b] = 0.f;
        {
            const float* hp = &hsh[kbase];
            #pragma unroll
            for (int i = 0; i < 4; ++i) {
                float4 hv[8];
                #pragma unroll
                for (int b = 0; b < 8; ++b)
                    hv[b] = *(const float4*)&hp[b * HID + i * 32];
                #pragma unroll
                for (int g = 0; g < 4; ++g) {
                    float4 uv = ureg[g][i];
                    #pragma unroll
                    for (int b = 0; b < 8; ++b)
                        accm[g][b] += uv.x * hv[b].x + uv.y * hv[b].y
                                    + uv.z * hv[b].z + uv.w * hv[b].w;
                }
                __builtin_amdgcn_sched_barrier(0);   // bound load-hoist liveness
            }
        }

        // ---- fold the kq-octet (lane bits 0..2) inside the wave
        #pragma unroll
        for (int g = 0; g < 4; ++g)
            #pragma unroll
            for (int b = 0; b < 8; ++b) {
                float v = accm[g][b];
                v += __shfl_xor(v, 1);
                v += __shfl_xor(v, 2);
                v += __shfl_xor(v, 4);
                accm[g][b] = v;
            }
        if (kq == 0) {
            #pragma unroll
            for (int g = 0; g < 4; ++g) {
                *(float4*)&red[wv][gg][g][0] =
                    make_float4(accm[g][0], accm[g][1], accm[g][2], accm[g][3]);
                *(float4*)&red[wv][gg][g][4] =
                    make_float4(accm[g][4], accm[g][5], accm[g][6], accm[g][7]);
            }
        }
        __syncthreads();

        // ---- gates + state update (128 threads)
        if (tid < BT * JT) {
            int bl = tid >> 4;
            int jl = tid & 15;
            float sa = 0.f, sz = 0.f;
            #pragma unroll
            for (int v = 0; v < 8; ++v) {
                sa += red[v][jl >> 2][jl & 3][bl];
                sz += red[v][4 + (jl >> 2)][jl & 3][bl];
            }
            float at = wa + sa;
            float zt = wz + sz;
            zt = 1.f / (1.f + expf(-zt));
            float hc = tanhf(at);
            float hold = hsh[bl * HID + j0 + jl];
            float hnew = zt * hold + (1.f - zt) * hc;
            int bg = bg0 + bl;
            out[((size_t)bg * TLEN + t) * HID + j0 + jl] = hnew;     // plain
            if (t < TLEN - 1) {
                st_h(&h_n[(size_t)bg * HID + j0 + jl], hnew);        // coherent
            } else {
                hlast[(size_t)bg * HID + j0 + jl] = hnew;
            }
        }

        // ---- publish: one store; 3-deep ring makes WAR free
        if (t < TLEN - 1) {
            __syncthreads();   // drains vmcnt -> h stores at LLC
            if (tid == 0) st_flag(&flags[wg * FSTRIDE], t + 1);
        }

        float* tmp = h_t; h_t = h_n; h_n = h_p; h_p = tmp;
    }
}

// ---------------------------------------------------------------------------
extern "C" void kernel_launch(void* const* d_in, const int* in_sizes, int n_in,
                              void* d_out, int out_size, void* d_ws, size_t ws_size,
                              hipStream_t stream) {
    (void)in_sizes; (void)n_in; (void)out_size; (void)ws_size;

    const float* x  = (const float*)d_in[0];
    const float* W0 = (const float*)d_in[1];
    const float* U0 = (const float*)d_in[2];
    const float* W1 = (const float*)d_in[3];
    const float* U1 = (const float*)d_in[4];

    float* out    = (float*)d_out;                              // [B,T,H]
    float* hstack = out + (size_t)BATCH * TLEN * HID;           // [2,B,H]

    int*   flags = (int*)d_ws;                                  // 256*16 ints
    float* hbuf  = (float*)d_ws + NWG * FSTRIDE;                // [3][B][H]
    float* wbuf  = hbuf + 3 * BHID;                             // [T][B][2H]

    dim3 gg(16384 / 128, 2048 / 128);
    int init_blocks = (BHID + 255) / 256;

    // ---- layer 0 ----
    proj_gemm<<<gg, 256, 0, stream>>>(x, W0, wbuf, 512);
    rec_init<<<init_blocks, 256, 0, stream>>>(hbuf, flags);
    ligru_rec<<<dim3(NWG), dim3(512), 0, stream>>>(wbuf, U0, hbuf, flags,
                                                   out, hstack);

    // ---- layer 1 ---- (reads layer-0 output staged in d_out, then overwrites)
    proj_gemm<<<gg, 256, 0, stream>>>(out, W1, wbuf, 1024);
    rec_init<<<init_blocks, 256, 0, stream>>>(hbuf, flags);
    ligru_rec<<<dim3(NWG), dim3(512), 0, stream>>>(wbuf, U1, hbuf, flags,
                                                   out, hstack + BATCH * HID);
}